// Round 3
// baseline (132.628 us; speedup 1.0000x reference)
//
#include <hip/hip_runtime.h>
#include <math.h>

typedef __attribute__((ext_vector_type(8))) _Float16 half8;
typedef __attribute__((ext_vector_type(4))) _Float16 half4;
typedef __attribute__((ext_vector_type(4))) float    f32x4;
typedef __attribute__((ext_vector_type(2))) float    f32x2;

#define TSTEPS 28
#define IDIM   28
#define HDIM   128
#define NKC    5       // K chunks of 32: 160 = 128 (h) + 28 (x) + bias(1) + 3 pad
#define TILE_B 32      // two independent 16-row streams per block
#define CDIM   10

#if __has_builtin(__builtin_amdgcn_exp2f)
#define EXP2F(x) __builtin_amdgcn_exp2f(x)
#else
#define EXP2F(x) exp2f(x)
#endif
#if __has_builtin(__builtin_amdgcn_rcpf)
#define RCPF(x) __builtin_amdgcn_rcpf(x)
#else
#define RCPF(x) (1.0f / (x))
#endif
#if __has_builtin(__builtin_amdgcn_s_setprio)
#define SETPRIO(p) __builtin_amdgcn_s_setprio(p)
#else
#define SETPRIO(p)
#endif

#define NLOG2E (-1.44269504f)
#define P2LOG2E (2.88539008f)

#define MFMA16(a,b,c) __builtin_amdgcn_mfma_f32_16x16x32_f16((a),(b),(c),0,0,0)

// P[kc][gate][n8][lane][j] (f16): B-fragment order for mfma_f32_16x16x32_f16.
// Activation scales folded (i,f,o x -log2e; g x 2log2e). Bias row at k=156
// (pairs with constant 1.0 in A column 156). k=157..159 zero.
__global__ __launch_bounds__(256) void pack_w(const float* __restrict__ Wih,
                                              const float* __restrict__ Whh,
                                              const float* __restrict__ bih,
                                              const float* __restrict__ bhh,
                                              _Float16* __restrict__ P) {
    int e = blockIdx.x * 256 + threadIdx.x;      // 5*4*8*64*8 = 81920
    if (e >= NKC * 4 * 8 * 64 * 8) return;
    int j  = e & 7;
    int ln = (e >> 3) & 63;
    int w  = (e >> 9) & 7;
    int t  = (e >> 12) & 3;
    int kc = e >> 14;
    int k  = kc * 32 + ((ln >> 4) << 3) + j;
    int u  = w * 16 + (ln & 15);
    int g  = t * HDIM + u;
    float v = 0.f;
    if (k < HDIM)                   v = Whh[g * HDIM + k];
    else if (k < HDIM + IDIM)       v = Wih[g * IDIM + (k - HDIM)];
    else if (k == HDIM + IDIM)      v = bih[g] + bhh[g];   // bias row
    float sc = (t == 2) ? P2LOG2E : NLOG2E;
    P[e] = (_Float16)(v * sc);
}

// Block = 2 independent 16-row LSTM streams (waves 0-3 = A, 4-7 = B).
// Wave w4 of a stream owns cols u in [32*w4, 32*w4+32) of ALL FOUR gates
// (8 col-tiles x 5 K-chunks = 40 MFMAs/step), so activation for its
// (row,u) elements is fully lane-local: no cross-wave exchange, only the
// h -> A-frag LDS redistribution needs the barrier. Streams run half a
// step out of phase: every barrier interval, each SIMD has one wave in
// MFMA role (wave k) and one in act role (wave k+4) -> MFMA/TRANS/VALU
// pipes are co-fed by the HW wave scheduler (the mechanism that worked
// in R0), not by compiler interleave (which failed in R1/R2).
__global__ __launch_bounds__(512, 2) void lstm_kernel(
    const float* __restrict__ x,          // [B][28][28] fp32
    const _Float16* __restrict__ P,       // packed weights, 160 KB
    const float* __restrict__ Wfc,        // [10][128]
    const float* __restrict__ b_fc,       // [10]
    float* __restrict__ out)              // [B][10]
{
    __shared__ __align__(16) _Float16 frag[2][NKC][64][8];     // 10 KB
    __shared__ __align__(16) float hplain[TILE_B][HDIM + 4];   // 16.9 KB

    const int tid = threadIdx.x;
    const int l   = tid & 63;
    const int w   = tid >> 6;                  // wave 0..7
    const int sid = w >> 2;                    // stream 0 (A) / 1 (B)
    const int w4  = w & 3;                     // wave-in-stream: col range
    const int b0  = blockIdx.x * TILE_B;

    // ---- per-wave B-frags in registers: 8 col-tiles x (4 h-kc + kc4) ----
    // breg[g][n][kc] covers gate g, cols 32*w4+16n .. +16, k-chunk kc.
    half8 breg[4][2][4];
    half8 breg4[4][2];
    {
        const half8* Pp = (const half8*)P;
        #pragma unroll
        for (int g = 0; g < 4; ++g)
            #pragma unroll
            for (int n = 0; n < 2; ++n) {
                #pragma unroll
                for (int kc = 0; kc < 4; ++kc)
                    breg[g][n][kc] = Pp[((kc * 4 + g) * 8 + (2 * w4 + n)) * 64 + l];
                breg4[g][n] = Pp[((4 * 4 + g) * 8 + (2 * w4 + n)) * 64 + l];
            }
    }

    // ---- init LDS: zero h-chunks of both streams; bias-1.0 column ----
    {
        float4 z = {0.f, 0.f, 0.f, 0.f};
        // stream A h-chunks = float4 idx [0,256); stream B = [320,576)
        ((float4*)frag)[(tid < 256) ? tid : (tid + 64)] = z;
    }
    if (tid < 32) {   // k=156 -> 1.0, k=157..159 -> 0 (slots 48..63, j=4..7)
        int s = tid >> 4, i = tid & 15;
        half4 onev = {(_Float16)1.f, (_Float16)0.f, (_Float16)0.f, (_Float16)0.f};
        *(half4*)&frag[s][4][48 + i][4] = onev;
    }

    // ---- x loaders: 112 threads per stream (waves 0-1 / 4-5) ----
    const int xid   = tid & 255;
    const bool xact = (xid < 112);
    const int xrow  = xid / 7, xg = xid % 7;
    const int xslot = xrow + 16 * (xg >> 1);
    const int xoff  = (xg & 1) * 4;
    const float4* xs4 = (const float4*)(x + (size_t)(b0 + sid * 16 + xrow) * (TSTEPS * IDIM));
    float4 xh;
    if (xact) {
        float4 x0 = xs4[xg];                   // x(0)
        half4 h0 = {(_Float16)x0.x, (_Float16)x0.y, (_Float16)x0.z, (_Float16)x0.w};
        *(half4*)&frag[sid][4][xslot][xoff] = h0;
    }

    const int l15 = l & 15;
    const int mb  = (l >> 4) << 2;             // row base for C-layout
    const int jh  = l & 7;
    const int q0  = (l >> 3) & 1;
    _Float16 (*myfrag)[64][8] = frag[sid];

    f32x4 acc[4][2];                           // [gate][n] 16x16 C-tiles
    f32x2 cst[4];                              // cell state pairs [2n+rp]
    cst[0] = cst[1] = cst[2] = cst[3] = (f32x2){0.f, 0.f};
    const f32x4 zc = {0.f, 0.f, 0.f, 0.f};

    // ---- MFMA role: issue x(t+1) load; gates(t) = W.[h(t-1),x(t),1] ----
    auto mfma_phase = [&](int t) {
        if (xact && t + 1 < TSTEPS) xh = xs4[(t + 1) * 7 + xg];
        half8 a0 = *(const half8*)&myfrag[0][l][0];
        half8 a1 = *(const half8*)&myfrag[1][l][0];
        half8 a2 = *(const half8*)&myfrag[2][l][0];
        half8 a3 = *(const half8*)&myfrag[3][l][0];
        half8 a4 = *(const half8*)&myfrag[4][l][0];
        SETPRIO(1);
        #pragma unroll
        for (int g = 0; g < 4; ++g)
            #pragma unroll
            for (int n = 0; n < 2; ++n) {
                f32x4 c = MFMA16(a4, breg4[g][n], zc);   // x + bias (no zeroing)
                c = MFMA16(a0, breg[g][n][0], c);
                c = MFMA16(a1, breg[g][n][1], c);
                c = MFMA16(a2, breg[g][n][2], c);
                c = MFMA16(a3, breg[g][n][3], c);
                acc[g][n] = c;
            }
        SETPRIO(0);
    };

    // ---- act role: 8 elems/lane; h -> own kc chunk (kc == w4); commit x ----
    auto act_phase = [&](int t) {
        const bool lastT = (t == TSTEPS - 1);
        #pragma unroll
        for (int n = 0; n < 2; ++n) {
            float hv[4];
            #pragma unroll
            for (int rp = 0; rp < 2; ++rp) {
                const int r0 = rp * 2, r1 = r0 + 1;
                f32x2 Ei = {EXP2F(acc[0][n][r0]), EXP2F(acc[0][n][r1])};  // e^{-i}
                f32x2 Ef = {EXP2F(acc[1][n][r0]), EXP2F(acc[1][n][r1])};  // e^{-f}
                f32x2 Eg = {EXP2F(acc[2][n][r0]), EXP2F(acc[2][n][r1])};  // e^{2g}
                f32x2 Eo = {EXP2F(acc[3][n][r0]), EXP2F(acc[3][n][r1])};  // e^{-o}
                f32x2 one = {1.f, 1.f};
                f32x2 Di = Ei + one, Df = Ef + one, Dg = Eg + one, Do = Eo + one;
                f32x2 Pif = Di * Df, Pgo = Dg * Do;
                f32x2 Rif = {RCPF(Pif.x), RCPF(Pif.y)};
                f32x2 Rgo = {RCPF(Pgo.x), RCPF(Pgo.y)};
                f32x2 is = Rif * Df, fs = Rif * Di;
                f32x2 gt = one - 2.f * (Rgo * Do);
                f32x2 os = Rgo * Dg;
                f32x2 c = fs * cst[2 * n + rp] + is * gt;
                cst[2 * n + rp] = c;
                f32x2 Etc = {EXP2F(c.x * P2LOG2E), EXP2F(c.y * P2LOG2E)};
                f32x2 Dtc = Etc + one;
                f32x2 Rtc = {RCPF(Dtc.x), RCPF(Dtc.y)};
                f32x2 tc = one - 2.f * Rtc;
                f32x2 h2 = os * tc;
                hv[r0] = h2.x; hv[r1] = h2.y;
            }
            if (lastT) {
                #pragma unroll
                for (int r = 0; r < 4; ++r)
                    hplain[sid * 16 + mb + r][32 * w4 + n * 16 + l15] = hv[r];
            } else {
                const int qn = q0 + 2 * n;
                #pragma unroll
                for (int r = 0; r < 4; ++r)
                    myfrag[w4][mb + r + 16 * qn][jh] = (_Float16)hv[r];
            }
        }
        if (xact && t + 1 < TSTEPS) {          // commit x(t+1) for next MFMA
            half4 hc = {(_Float16)xh.x, (_Float16)xh.y, (_Float16)xh.z, (_Float16)xh.w};
            *(half4*)&myfrag[4][xslot][xoff] = hc;
        }
    };

    __syncthreads();

    // phase 0: stream A computes gates(0); B idles (enters loop in MFMA role)
    if (sid == 0) mfma_phase(0);
    __syncthreads();

    for (int t = 0; t < TSTEPS; ++t) {
        // odd phase 2t+1: A act(t) || B MFMA(t)
        if (sid == 0) act_phase(t);
        else          mfma_phase(t);
        __syncthreads();
        // even phase 2t+2: A MFMA(t+1) || B act(t)
        if (sid == 0) { if (t + 1 < TSTEPS) mfma_phase(t + 1); }
        else          act_phase(t);
        __syncthreads();
    }

    // ---- FC + ReLU epilogue ----
    if (tid < TILE_B * CDIM) {
        int row = tid / CDIM, c = tid % CDIM;
        const float4* hv4 = (const float4*)&hplain[row][0];
        const float4* wf  = (const float4*)(Wfc + c * HDIM);
        float s = b_fc[c];
        #pragma unroll
        for (int q = 0; q < 32; ++q) {
            float4 a4 = hv4[q], b4 = wf[q];
            s += a4.x * b4.x + a4.y * b4.y + a4.z * b4.z + a4.w * b4.w;
        }
        out[(size_t)(b0 + row) * CDIM + c] = fmaxf(s, 0.f);
    }
}

extern "C" void kernel_launch(void* const* d_in, const int* in_sizes, int n_in,
                              void* d_out, int out_size, void* d_ws, size_t ws_size,
                              hipStream_t stream) {
    const float* x   = (const float*)d_in[0];
    const float* Wih = (const float*)d_in[1];
    const float* Whh = (const float*)d_in[2];
    const float* bih = (const float*)d_in[3];
    const float* bhh = (const float*)d_in[4];
    const float* Wfc = (const float*)d_in[5];
    const float* bfc = (const float*)d_in[6];
    float* out = (float*)d_out;
    _Float16* P = (_Float16*)d_ws;     // 160 KB packed weights

    hipLaunchKernelGGL(pack_w, dim3(320), dim3(256), 0, stream, Wih, Whh, bih, bhh, P);
    hipLaunchKernelGGL(lstm_kernel, dim3(8192 / TILE_B), dim3(512), 0, stream,
                       x, P, Wfc, bfc, out);
}